// Round 6
// baseline (267.488 us; speedup 1.0000x reference)
//
#include <hip/hip_runtime.h>
#include <math.h>

// LipschitzNorm: E=800000 edges, N=50000 nodes, H=4 heads, D=32 dims (fp32).
// out[e,h] = alpha[e,h] / (natt[h] * sqrt(g[e] + ||x[e,h]||^2) + EPS)
//   natt[h] = 4 * ||concat(att_l[h], att_r[h])||
//   g[e]    = segment_max(||x||^2, index).flat[index[e]]   (faithful view(-1,1) bug)
// Only flat table positions < N are gathered -> only nodes < N/H=12500 matter.
//
// R6: single fused kernel with a hand-rolled grid barrier. Per-edge norms stay
// in REGISTERS across the barrier (kills the 25.6MB norm_x round-trip + 3.2MB
// index re-read + one dispatch). Co-residency: 512 blocks @ launch_bounds(256,2)
// = 2 blocks/CU on 256 CUs, verified per call via occupancy query; otherwise
// fall back to the proven R5 two-kernel path.

static constexpr int   H_        = 4;
static constexpr int   D_        = 32;
static constexpr int   N_NODES   = 50000;
static constexpr int   N_LIVE    = N_NODES / H_;   // 12500
static constexpr float ATT_NORM_ = 4.0f;
static constexpr float EPS_      = 1e-12f;
static constexpr int   TPB_      = 256;
static constexpr int   FBLK_     = 512;            // 2 blocks/CU * 256 CUs
static constexpr int   FITERS_   = 7;              // ceil(800000 / (512*256))

__global__ void __launch_bounds__(TPB_, 2)
k_fused(const float4* __restrict__ x4,
        const int*    __restrict__ index,
        const float*  __restrict__ att_l,
        const float*  __restrict__ att_r,
        int*          __restrict__ table,    // [N_NODES] float-as-int, pre-zeroed
        int*          __restrict__ counter,  // pre-zeroed
        const float4* __restrict__ alpha4,
        float4*       __restrict__ out4,
        int E) {
    __shared__ float s_natt[H_];
    if (threadIdx.x < H_) {
        const int h = threadIdx.x;
        float s = 0.f;
        #pragma unroll
        for (int d = 0; d < D_; ++d) {
            const float a = att_l[h * D_ + d];
            const float b = att_r[h * D_ + d];
            s += a * a + b * b;
        }
        s_natt[h] = ATT_NORM_ * sqrtf(s);
    }

    const int T   = FBLK_ * TPB_;
    const int tid = blockIdx.x * TPB_ + threadIdx.x;

    // Phase A: per-edge per-head squared norms; keep in registers; scatter-max.
    float sq[FITERS_][H_];          // fully unrolled -> static indexing (no scratch)
    int   idx[FITERS_];
    #pragma unroll
    for (int it = 0; it < FITERS_; ++it) {
        const int e = tid + it * T;
        if (e < E) {
            idx[it] = index[e];
            const float4* xb = x4 + (size_t)e * (H_ * D_ / 4);
            #pragma unroll
            for (int h = 0; h < H_; ++h) {
                float s = 0.f;
                #pragma unroll
                for (int j = 0; j < D_ / 4; ++j) {
                    const float4 u = xb[h * (D_ / 4) + j];
                    s += u.x * u.x + u.y * u.y + u.z * u.z + u.w * u.w;
                }
                sq[it][h] = s;
            }
            if (idx[it] < N_LIVE) {   // only gathered nodes matter (also bounds table)
                #pragma unroll
                for (int h = 0; h < H_; ++h)
                    atomicMax(table + idx[it] * H_ + h, __float_as_int(sq[it][h]));
            }
        } else {
            idx[it] = 0;
            #pragma unroll
            for (int h = 0; h < H_; ++h) sq[it][h] = 0.f;
        }
    }

    // ---- grid-wide barrier (all FBLK_ blocks co-resident by construction) ----
    __threadfence();                 // each thread releases its own atomics/stores
    __syncthreads();                 // drains this block's vmcnt before arrive
    if (threadIdx.x == 0) {
        atomicAdd(counter, 1);
        while (__hip_atomic_load(counter, __ATOMIC_RELAXED,
                                 __HIP_MEMORY_SCOPE_AGENT) < FBLK_)
            __builtin_amdgcn_s_sleep(4);
    }
    __syncthreads();
    __threadfence();                 // acquire

    // Phase B: flat-gather (agent scope: past the non-coherent per-XCD L2),
    // finish, store.
    const float n0 = s_natt[0], n1 = s_natt[1], n2 = s_natt[2], n3 = s_natt[3];
    #pragma unroll
    for (int it = 0; it < FITERS_; ++it) {
        const int e = tid + it * T;
        if (e < E) {
            int gb = __hip_atomic_load(table + idx[it], __ATOMIC_RELAXED,
                                       __HIP_MEMORY_SCOPE_AGENT);
            gb = gb < 0 ? 0 : gb;    // unwritten entry -> 0.0f
            const float g = __int_as_float(gb);
            const float4 al = alpha4[e];
            float4 o;
            o.x = al.x / (n0 * sqrtf(g + sq[it][0]) + EPS_);
            o.y = al.y / (n1 * sqrtf(g + sq[it][1]) + EPS_);
            o.z = al.z / (n2 * sqrtf(g + sq[it][2]) + EPS_);
            o.w = al.w / (n3 * sqrtf(g + sq[it][3]) + EPS_);
            out4[e] = o;
        }
    }
}

// ---------- fallback: proven R5 two-kernel path ----------
__global__ void __launch_bounds__(256)
k_norm_scatter(const float* __restrict__ x,
               const int* __restrict__ index,
               const float* __restrict__ att_l,
               const float* __restrict__ att_r,
               float* __restrict__ max_norm,
               float* __restrict__ norm_x,
               float* __restrict__ natt,
               int EH) {
    if (blockIdx.x == 0 && threadIdx.x < H_) {
        const int h = threadIdx.x;
        float s = 0.f;
        #pragma unroll
        for (int d = 0; d < D_; ++d) {
            const float a = att_l[h * D_ + d];
            const float b = att_r[h * D_ + d];
            s += a * a + b * b;
        }
        natt[h] = ATT_NORM_ * sqrtf(s);
    }
    const int p = blockIdx.x * blockDim.x + threadIdx.x;
    if (p >= EH) return;
    const float4* xv = reinterpret_cast<const float4*>(x) + (size_t)p * (D_ / 4);
    float s = 0.f;
    #pragma unroll
    for (int j = 0; j < D_ / 4; ++j) {
        const float4 v = xv[j];
        s += v.x * v.x + v.y * v.y + v.z * v.z + v.w * v.w;
    }
    norm_x[p] = s;
    const int e = p >> 2;
    const int h = p & 3;
    const int n = index[e];
    if (n < N_LIVE)
        atomicMax(reinterpret_cast<int*>(max_norm) + n * H_ + h, __float_as_int(s));
}

__global__ void __launch_bounds__(256)
k_output(const float* __restrict__ alpha,
         const int* __restrict__ index,
         const float* __restrict__ max_norm,
         const float* __restrict__ norm_x,
         const float* __restrict__ natt,
         float* __restrict__ out,
         int E) {
    const int e = blockIdx.x * blockDim.x + threadIdx.x;
    if (e >= E) return;
    const float n0 = natt[0], n1 = natt[1], n2 = natt[2], n3 = natt[3];
    const float g = max_norm[index[e]];
    const float4 nx = reinterpret_cast<const float4*>(norm_x)[e];
    const float4 al = reinterpret_cast<const float4*>(alpha)[e];
    float4 o;
    o.x = al.x / (n0 * sqrtf(g + nx.x) + EPS_);
    o.y = al.y / (n1 * sqrtf(g + nx.y) + EPS_);
    o.z = al.z / (n2 * sqrtf(g + nx.z) + EPS_);
    o.w = al.w / (n3 * sqrtf(g + nx.w) + EPS_);
    reinterpret_cast<float4*>(out)[e] = o;
}

extern "C" void kernel_launch(void* const* d_in, const int* in_sizes, int n_in,
                              void* d_out, int out_size, void* d_ws, size_t ws_size,
                              hipStream_t stream) {
    const float* x     = (const float*)d_in[0];
    const float* att_l = (const float*)d_in[1];
    const float* att_r = (const float*)d_in[2];
    const float* alpha = (const float*)d_in[3];
    const int*   index = (const int*)d_in[4];

    const int E  = in_sizes[0] / (H_ * D_);
    const int EH = E * H_;

    char* wsb = (char*)d_ws;
    const size_t table_bytes = (size_t)N_NODES * sizeof(float);   // 200 KB
    float* table_f  = (float*)wsb;
    int*   table_i  = (int*)wsb;
    int*   counter  = (int*)(wsb + table_bytes);                  // 256B slot
    float* norm_x   = (float*)(wsb + table_bytes + 256);
    float* natt     = (float*)(wsb + table_bytes + 256 + (size_t)EH * sizeof(float));

    // zero table + barrier counter every call (harness does not re-poison).
    hipMemsetAsync(wsb, 0, table_bytes + 256, stream);

    // co-residency check each call (deterministic, capture-safe: no stream op).
    int nb = 0;
    hipError_t oerr = hipOccupancyMaxActiveBlocksPerMultiprocessor(&nb, k_fused, TPB_, 0);
    const bool use_fused = (oerr == hipSuccess) && (nb >= 2);

    if (use_fused) {
        const float4* x4 = (const float4*)x;
        const float4* a4 = (const float4*)alpha;
        float4*       o4 = (float4*)d_out;
        k_fused<<<FBLK_, TPB_, 0, stream>>>(x4, index, att_l, att_r,
                                            table_i, counter, a4, o4, E);
    } else {
        const int b = 256;
        k_norm_scatter<<<(EH + b - 1) / b, b, 0, stream>>>(
            x, index, att_l, att_r, table_f, norm_x, natt, EH);
        k_output<<<(E + b - 1) / b, b, 0, stream>>>(
            alpha, index, table_f, norm_x, natt, (float*)d_out, E);
    }
}

// Round 7
// 98.100 us; speedup vs baseline: 2.7267x; 2.7267x over previous
//
#include <hip/hip_runtime.h>
#include <hip/hip_fp16.h>
#include <math.h>

// LipschitzNorm: E=800000 edges, N=50000 nodes, H=4 heads, D=32 dims (fp32).
// out[e,h] = alpha[e,h] / (natt[h] * sqrt(g[e] + ||x[e,h]||^2) + EPS)
//   natt[h] = 4 * ||concat(att_l[h], att_r[h])||
//   g[e]    = segment_max(||x||^2, index).flat[index[e]]   (faithful view(-1,1) bug)
// Only flat table positions < N are gathered -> only nodes < N/H=12500 matter.
//
// R7 = R5 structure (proven 98.5us; fused R6 was latency-bound at 24% occupancy)
// + two byte/ILP micro-opts:
//   (a) norm_x stored as fp16 (round-trip 25.6MB -> 12.8MB). Error: delta_s ~
//       s*2^-11 ~ 0.01 on (g+s) ~ 64 -> delta_out ~ 8e-5 relative; threshold 3.8e-4 abs.
//   (b) pass B: 2 edges/thread (int2 index, uint4 norm-halves, 2x float4 alpha/out)
//       for independent gather chains.

static constexpr int   H_        = 4;
static constexpr int   D_        = 32;
static constexpr int   N_NODES   = 50000;
static constexpr int   N_LIVE    = N_NODES / H_;   // 12500
static constexpr float ATT_NORM_ = 4.0f;
static constexpr float EPS_      = 1e-12f;

__global__ void __launch_bounds__(256)
k_norm_scatter(const float* __restrict__ x,
               const int* __restrict__ index,
               const float* __restrict__ att_l,
               const float* __restrict__ att_r,
               float* __restrict__ max_norm,   // [N_NODES] flat floats, pre-zeroed
               __half* __restrict__ norm_h,    // [E*H] fp16
               float* __restrict__ natt,       // [H]
               int EH) {
    if (blockIdx.x == 0 && threadIdx.x < H_) {
        const int h = threadIdx.x;
        float s = 0.f;
        #pragma unroll
        for (int d = 0; d < D_; ++d) {
            const float a = att_l[h * D_ + d];
            const float b = att_r[h * D_ + d];
            s += a * a + b * b;
        }
        natt[h] = ATT_NORM_ * sqrtf(s);
    }
    const int p = blockIdx.x * blockDim.x + threadIdx.x;   // pair id = e*H + h
    if (p >= EH) return;

    const float4* xv = reinterpret_cast<const float4*>(x) + (size_t)p * (D_ / 4);
    float s = 0.f;
    #pragma unroll
    for (int j = 0; j < D_ / 4; ++j) {
        const float4 v = xv[j];
        s += v.x * v.x + v.y * v.y + v.z * v.z + v.w * v.w;
    }
    norm_h[p] = __float2half_rn(s);            // 2B/lane, coalesced

    const int e = p >> 2;      // H_ == 4
    const int h = p & 3;
    const int n = index[e];
    // Only nodes n < N_LIVE are ever gathered (flat view bug). Skip the rest.
    if (n < N_LIVE) {
        // s >= 0 and table pre-zeroed: int-compare == float-compare.
        atomicMax(reinterpret_cast<int*>(max_norm) + n * H_ + h, __float_as_int(s));
    }
}

// Pass B: 2 edges per thread for gather ILP.
__global__ void __launch_bounds__(256)
k_output(const float4* __restrict__ alpha4,   // [E]
         const int*    __restrict__ index,
         const float*  __restrict__ max_norm, // flat, first 50000 valid
         const uint2*  __restrict__ normh2,   // [E] (4 halfs per edge)
         const float*  __restrict__ natt,     // [H]
         float4*       __restrict__ out4,     // [E]
         int E) {
    const int t  = blockIdx.x * blockDim.x + threadIdx.x;
    const int e0 = t * 2;
    if (e0 >= E) return;
    const bool two = (e0 + 1 < E);

    const float n0 = natt[0], n1 = natt[1], n2 = natt[2], n3 = natt[3];

    // paired loads (consecutive addresses -> coalesced wide)
    const int i0 = index[e0];
    const int i1 = two ? index[e0 + 1] : 0;
    const float g0 = max_norm[i0];             // independent gather chains
    const float g1 = two ? max_norm[i1] : 0.f;

    const uint4 nh = *reinterpret_cast<const uint4*>(normh2 + e0);  // e0: x,y  e1: z,w
    const float4 a0 = alpha4[e0];

    const float2 s01 = __half22float2(*reinterpret_cast<const __half2*>(&nh.x));
    const float2 s23 = __half22float2(*reinterpret_cast<const __half2*>(&nh.y));
    float4 o0;
    o0.x = a0.x / (n0 * sqrtf(g0 + s01.x) + EPS_);
    o0.y = a0.y / (n1 * sqrtf(g0 + s01.y) + EPS_);
    o0.z = a0.z / (n2 * sqrtf(g0 + s23.x) + EPS_);
    o0.w = a0.w / (n3 * sqrtf(g0 + s23.y) + EPS_);
    out4[e0] = o0;

    if (two) {
        const float4 a1 = alpha4[e0 + 1];
        const float2 s45 = __half22float2(*reinterpret_cast<const __half2*>(&nh.z));
        const float2 s67 = __half22float2(*reinterpret_cast<const __half2*>(&nh.w));
        float4 o1;
        o1.x = a1.x / (n0 * sqrtf(g1 + s45.x) + EPS_);
        o1.y = a1.y / (n1 * sqrtf(g1 + s45.y) + EPS_);
        o1.z = a1.z / (n2 * sqrtf(g1 + s67.x) + EPS_);
        o1.w = a1.w / (n3 * sqrtf(g1 + s67.y) + EPS_);
        out4[e0 + 1] = o1;
    }
}

extern "C" void kernel_launch(void* const* d_in, const int* in_sizes, int n_in,
                              void* d_out, int out_size, void* d_ws, size_t ws_size,
                              hipStream_t stream) {
    const float* x     = (const float*)d_in[0];
    const float* att_l = (const float*)d_in[1];
    const float* att_r = (const float*)d_in[2];
    const float* alpha = (const float*)d_in[3];
    const int*   index = (const int*)d_in[4];

    const int E  = in_sizes[0] / (H_ * D_);
    const int EH = E * H_;

    char* wsb = (char*)d_ws;
    const size_t table_bytes = (size_t)N_NODES * sizeof(float);      // 200 KB
    float*  max_norm = (float*)wsb;
    __half* norm_h   = (__half*)(wsb + table_bytes);                 // 6.4 MB
    float*  natt     = (float*)(wsb + table_bytes + (size_t)EH * sizeof(__half));

    // zero the gathered part of the scatter-max table every call.
    hipMemsetAsync(max_norm, 0, table_bytes, stream);

    const int b = 256;
    k_norm_scatter<<<(EH + b - 1) / b, b, 0, stream>>>(
        x, index, att_l, att_r, max_norm, norm_h, natt, EH);
    const int nt = (E + 1) / 2;                 // 2 edges per thread
    k_output<<<(nt + b - 1) / b, b, 0, stream>>>(
        (const float4*)alpha, index, max_norm, (const uint2*)norm_h, natt,
        (float4*)d_out, E);
}